// Round 7
// baseline (175.113 us; speedup 1.0000x reference)
//
#include <hip/hip_runtime.h>

typedef short  short8  __attribute__((ext_vector_type(8)));
typedef short  short4v __attribute__((ext_vector_type(4)));
typedef float  float4v __attribute__((ext_vector_type(4)));
typedef int    int4v   __attribute__((ext_vector_type(4)));
typedef int    int2v   __attribute__((ext_vector_type(2)));

#define LOG2E 1.4426950408889634f

static __device__ __forceinline__ short f2bf(float f) {
  unsigned u = __builtin_bit_cast(unsigned, f);
  u = (u + 0x7fffu + ((u >> 16) & 1u)) >> 16;   // RNE
  return (short)u;
}
static __device__ __forceinline__ float bf2f(short s) {
  return __builtin_bit_cast(float, ((unsigned)(unsigned short)s) << 16);
}

// ---------------------------------------------------------------------------
// Kernel 1: h = x @ w.T  (8192x256, K=256), hi/lo bf16-split MFMA for ~f32
// accuracy. Writes hT bf16 [256][8192] (ws) and hT f32 [256][8192] (d_out,
// transient — consumed by k_scores1; d_out is fully rewritten by k_out).
// ---------------------------------------------------------------------------
__global__ __launch_bounds__(256) void k_hgemm(
    const float* __restrict__ x, const float* __restrict__ w,
    short* __restrict__ hT, float* __restrict__ hTf) {
  const int I0   = blockIdx.x * 64;
  const int lane = threadIdx.x & 63;
  const int wn   = threadIdx.x >> 6;       // 4 waves split N (cols)
  const int lrow = lane & 15;
  const int lk8  = (lane >> 4) << 3;

  float4v zero4 = {0.f, 0.f, 0.f, 0.f};
  float4v acc[4][4];
  #pragma unroll
  for (int mi = 0; mi < 4; ++mi)
    #pragma unroll
    for (int ni = 0; ni < 4; ++ni) acc[mi][ni] = zero4;

  for (int k0 = 0; k0 < 256; k0 += 32) {
    short8 ah[4], al[4], bh[4], bl[4];
    #pragma unroll
    for (int mi = 0; mi < 4; ++mi) {
      const float* xp = x + (size_t)(I0 + mi * 16 + lrow) * 256 + k0 + lk8;
      float4v va = *(const float4v*)xp;
      float4v vb = *(const float4v*)(xp + 4);
      #pragma unroll
      for (int e = 0; e < 4; ++e) {
        short h = f2bf(va[e]); ah[mi][e] = h;     al[mi][e]     = f2bf(va[e] - bf2f(h));
        h = f2bf(vb[e]);       ah[mi][4 + e] = h; al[mi][4 + e] = f2bf(vb[e] - bf2f(h));
      }
    }
    #pragma unroll
    for (int ni = 0; ni < 4; ++ni) {
      const float* wp = w + (size_t)(wn * 64 + ni * 16 + lrow) * 256 + k0 + lk8;
      float4v va = *(const float4v*)wp;
      float4v vb = *(const float4v*)(wp + 4);
      #pragma unroll
      for (int e = 0; e < 4; ++e) {
        short h = f2bf(va[e]); bh[ni][e] = h;     bl[ni][e]     = f2bf(va[e] - bf2f(h));
        h = f2bf(vb[e]);       bh[ni][4 + e] = h; bl[ni][4 + e] = f2bf(vb[e] - bf2f(h));
      }
    }
    #pragma unroll
    for (int mi = 0; mi < 4; ++mi)
      #pragma unroll
      for (int ni = 0; ni < 4; ++ni) {
        acc[mi][ni] = __builtin_amdgcn_mfma_f32_16x16x32_bf16(al[mi], bh[ni], acc[mi][ni], 0, 0, 0);
        acc[mi][ni] = __builtin_amdgcn_mfma_f32_16x16x32_bf16(ah[mi], bl[ni], acc[mi][ni], 0, 0, 0);
        acc[mi][ni] = __builtin_amdgcn_mfma_f32_16x16x32_bf16(ah[mi], bh[ni], acc[mi][ni], 0, 0, 0);
      }
  }
  const int r0 = (lane >> 4) << 2;   // C/D: col=lane&15, row=(lane>>4)*4+reg
  #pragma unroll
  for (int mi = 0; mi < 4; ++mi)
    #pragma unroll
    for (int ni = 0; ni < 4; ++ni) {
      const int c   = wn * 64 + ni * 16 + lrow;
      const int row = I0 + mi * 16 + r0;
      float4v v = acc[mi][ni];
      short4v sv;
      #pragma unroll
      for (int r = 0; r < 4; ++r) sv[r] = f2bf(v[r]);
      *(short4v*)(hT + (size_t)c * 8192 + row) = sv;
      *(float4v*)(hTf + (size_t)c * 8192 + row) = v;
    }
}

// ---------------------------------------------------------------------------
// Kernel 2: s1 = h@a1, s2 = h@a2 partials (split-K = 2)
// ---------------------------------------------------------------------------
__global__ __launch_bounds__(256) void k_scores1(
    const float* __restrict__ hTf, const float* __restrict__ a,
    float* __restrict__ t1p, float* __restrict__ t2p) {
  const int i = blockIdx.x * 256 + threadIdx.x;
  const int q = blockIdx.y;
  float s1 = 0.f, s2 = 0.f;
  #pragma unroll 8
  for (int kf = q * 128; kf < q * 128 + 128; ++kf) {
    float hv = hTf[(size_t)kf * 8192 + i];
    s1 = fmaf(hv, a[kf], s1);
    s2 = fmaf(hv, a[256 + kf], s2);
  }
  t1p[q * 8192 + i] = s1;
  t2p[q * 8192 + i] = s2;
}

// ---------------------------------------------------------------------------
// Kernel 3: reduce partials, emit exp2 tables:
//   e1f1[i] = {exp2(t1c), exp2(0.2 t1c)},  ef2[j] = {exp2(t2c), exp2(0.2 t2c)}
// so W = adj ? max(e1*e2, f1*f2) : 1   (exp2(max(sc,0.2sc)) separable via
// monotonicity of exp2 — no per-element transcendental in k_gat).
// ---------------------------------------------------------------------------
__global__ __launch_bounds__(256) void k_scores2(
    const float* __restrict__ t1p, const float* __restrict__ t2p,
    float2* __restrict__ e1f1, float2* __restrict__ ef2) {
  const int i = blockIdx.x * 256 + threadIdx.x;
  const float t1 = LOG2E * (t1p[i] + t1p[8192 + i]);
  const float t2 = LOG2E * (t2p[i] + t2p[8192 + i]);
  e1f1[i] = make_float2(exp2f(t1), exp2f(0.2f * t1));
  ef2[i]  = make_float2(exp2f(t2), exp2f(0.2f * t2));
}

// ---------------------------------------------------------------------------
// Kernel 4: fused GAT GEMM, tuned for 2 blocks/CU co-residency (the r6
// bottleneck was barrier-drain latency with 1 block/CU and nothing to
// overlap). BM=128 x BN=256 x BK=32, split-K=8: grid (64,8) = 512 blocks =
// 2/CU; LDS 48KB (Wb 2x8K + Hb 2x16K, all double-buffered); launch_bounds
// (512,4) caps VGPR at 128. ONE barrier per step, and loads for step s+1
// are issued AFTER it (consumed before the next one), so the barrier's
// vmcnt(0) drain has nothing outstanding — global latency is covered by
// the frag-read+MFMA phase plus the co-resident block. Z accumulated as
// per-thread scalars (no Z-MFMA), reduced via LDS at the end. Partials
// written directly to ws (no atomics, no memsets).
// ---------------------------------------------------------------------------
__global__ __launch_bounds__(512, 4) void k_gat(
    const int* __restrict__ adj, const short* __restrict__ hT,
    const float2* __restrict__ e1f1, const float2* __restrict__ ef2,
    float* __restrict__ Np, float* __restrict__ Zp) {
  __shared__ __align__(16) char Wb[2][8192];    // [128 r][32 j] bf16, swz
  __shared__ __align__(16) char Hb[2][16384];   // [256 f][32 j] bf16, swz

  const int tid = threadIdx.x, lane = tid & 63, wave = tid >> 6;
  const int wm = wave >> 2, wn = wave & 3;
  const int lrow = lane & 15, lk16 = (lane >> 4) << 4;   // k byte-offset
  const int I0 = blockIdx.x * 128;
  const int j0 = blockIdx.y * 1024;

  // staging maps (2 row-passes each)
  const int ar = tid >> 3, ajc = (tid & 7) * 4;    // adj: rows ar, ar+64
  const int hf = tid >> 2, hjc = (tid & 3) * 8;    // hT:  f   hf, hf+128

  const int*   agp = adj + (size_t)(I0 + ar) * 8192 + j0 + ajc;
  const short* hgp = hT + (size_t)hf * 8192 + j0 + hjc;
  const float4v* ef4 = (const float4v*)ef2;
  const int efb = (j0 >> 1) + (tid & 7) * 2;

  float e1p0, f1p0, e1p1, f1p1;
  { float2 v0 = e1f1[I0 + ar];      e1p0 = v0.x; f1p0 = v0.y;
    float2 v1 = e1f1[I0 + 64 + ar]; e1p1 = v1.x; f1p1 = v1.y; }

  // LDS offsets (rows are 64B; XOR swizzle folds row&3 into the 16B-chunk)
  const int wwo = ar * 64 + ((ajc * 2) ^ ((ar & 3) << 4));
  const int hwo = hf * 64 + ((hjc * 2) ^ ((hf & 3) << 4));
  const int aro = (wm * 64 + lrow) * 64 + (lk16 ^ ((lrow & 3) << 4));
  const int bro = (wn * 64 + lrow) * 64 + (lk16 ^ ((lrow & 3) << 4));

  float4v zero4 = {0.f, 0.f, 0.f, 0.f};
  float4v acc[4][4];
  #pragma unroll
  for (int mi = 0; mi < 4; ++mi)
    #pragma unroll
    for (int ni = 0; ni < 4; ++ni) acc[mi][ni] = zero4;
  float zacc0 = 0.f, zacc1 = 0.f;

  // prologue: step-0 loads
  int4v  ga0 = *(const int4v*)(agp);
  int4v  ga1 = *(const int4v*)(agp + 524288);      // +64 rows
  short8 gh0 = *(const short8*)(hgp);
  short8 gh1 = *(const short8*)(hgp + 1048576);    // +128 f

  #pragma unroll 2
  for (int s = 0; s < 32; ++s) {
    // W-compute for step s (ef table loads are tiny + L1-hot)
    const float4v ge0 = ef4[efb + s * 16];
    const float4v ge1 = ef4[efb + s * 16 + 1];
    int2v pw0, pw1;
    {
      float w0 = ga0[0] ? fmaxf(e1p0 * ge0[0], f1p0 * ge0[1]) : 1.0f;
      float w1 = ga0[1] ? fmaxf(e1p0 * ge0[2], f1p0 * ge0[3]) : 1.0f;
      float w2 = ga0[2] ? fmaxf(e1p0 * ge1[0], f1p0 * ge1[1]) : 1.0f;
      float w3 = ga0[3] ? fmaxf(e1p0 * ge1[2], f1p0 * ge1[3]) : 1.0f;
      zacc0 += (w0 + w1) + (w2 + w3);
      asm("v_cvt_pk_bf16_f32 %0, %1, %2" : "=v"(pw0[0]) : "v"(w0), "v"(w1));
      asm("v_cvt_pk_bf16_f32 %0, %1, %2" : "=v"(pw0[1]) : "v"(w2), "v"(w3));
    }
    {
      float w0 = ga1[0] ? fmaxf(e1p1 * ge0[0], f1p1 * ge0[1]) : 1.0f;
      float w1 = ga1[1] ? fmaxf(e1p1 * ge0[2], f1p1 * ge0[3]) : 1.0f;
      float w2 = ga1[2] ? fmaxf(e1p1 * ge1[0], f1p1 * ge1[1]) : 1.0f;
      float w3 = ga1[3] ? fmaxf(e1p1 * ge1[2], f1p1 * ge1[3]) : 1.0f;
      zacc1 += (w0 + w1) + (w2 + w3);
      asm("v_cvt_pk_bf16_f32 %0, %1, %2" : "=v"(pw1[0]) : "v"(w0), "v"(w1));
      asm("v_cvt_pk_bf16_f32 %0, %1, %2" : "=v"(pw1[1]) : "v"(w2), "v"(w3));
    }

    // stage to the s-parity buffers (writes race nothing: readers of this
    // buffer last touched it at step s-2, separated by barrier(s-1))
    char* wbuf = Wb[0] + (s & 1) * 8192;
    char* hbuf = Hb[0] + (s & 1) * 16384;
    *(int2v*)(wbuf + wwo)          = pw0;
    *(int2v*)(wbuf + 4096 + wwo)   = pw1;   // +64 rows
    *(short8*)(hbuf + hwo)         = gh0;
    *(short8*)(hbuf + 8192 + hwo)  = gh1;   // +128 f
    __syncthreads();   // nothing outstanding in vmcnt here — cheap drain

    // issue step-s+1 globals now; latency hides under frag reads + MFMA
    const int sno = ((s + 1) & 31) * 32;
    ga0 = *(const int4v*)(agp + sno);
    ga1 = *(const int4v*)(agp + 524288 + sno);
    gh0 = *(const short8*)(hgp + sno);
    gh1 = *(const short8*)(hgp + 1048576 + sno);

    // fragment reads (conflict-free) + 16 MFMA
    short8 af[4], bf[4];
    #pragma unroll
    for (int mi = 0; mi < 4; ++mi) af[mi] = *(const short8*)(wbuf + aro + mi * 1024);
    #pragma unroll
    for (int ni = 0; ni < 4; ++ni) bf[ni] = *(const short8*)(hbuf + bro + ni * 1024);
    #pragma unroll
    for (int mi = 0; mi < 4; ++mi)
      #pragma unroll
      for (int ni = 0; ni < 4; ++ni)
        acc[mi][ni] = __builtin_amdgcn_mfma_f32_16x16x32_bf16(af[mi], bf[ni], acc[mi][ni], 0, 0, 0);
  }

  // Z reduce: per-thread scalars -> LDS -> 1 value per row
  __syncthreads();
  float* zl = (float*)Wb;                    // 128 x 8 floats
  zl[ar * 8 + (tid & 7)]        = zacc0;
  zl[(64 + ar) * 8 + (tid & 7)] = zacc1;
  __syncthreads();
  if (tid < 128) {
    float z = 0.f;
    #pragma unroll
    for (int g = 0; g < 8; ++g) z += zl[tid * 8 + g];
    Zp[(size_t)blockIdx.y * 8192 + I0 + tid] = z;
  }

  // N partial store (direct, no atomics)
  float* Npb = Np + (size_t)blockIdx.y * 2097152;
  const int r0 = (lane >> 4) << 2;
  #pragma unroll
  for (int mi = 0; mi < 4; ++mi) {
    const int rowb = I0 + wm * 64 + mi * 16 + r0;
    #pragma unroll
    for (int ni = 0; ni < 4; ++ni) {
      const int col = wn * 64 + ni * 16 + lrow;
      #pragma unroll
      for (int r = 0; r < 4; ++r)
        Npb[(size_t)(rowb + r) * 256 + col] = acc[mi][ni][r];
    }
  }
}

// ---------------------------------------------------------------------------
// Kernel 5: out = elu( (sum_y Np) / (sum_y Zp) )
// ---------------------------------------------------------------------------
__global__ __launch_bounds__(256) void k_out(
    const float* __restrict__ Np, const float* __restrict__ Zp,
    float* __restrict__ out) {
  const int idx = blockIdx.x * 256 + threadIdx.x;   // float4 index
  const int i = idx >> 6;                           // row (256 feat = 64 f4)
  float z = 0.f;
  #pragma unroll
  for (int y = 0; y < 8; ++y) z += Zp[y * 8192 + i];
  float4v n = {0.f, 0.f, 0.f, 0.f};
  #pragma unroll
  for (int y = 0; y < 8; ++y) {
    float4v v = ((const float4v*)Np)[(size_t)y * 524288 + idx];
    #pragma unroll
    for (int e = 0; e < 4; ++e) n[e] += v[e];
  }
  const float rz = 1.0f / z;
  float4v o;
  #pragma unroll
  for (int e = 0; e < 4; ++e) {
    float v = n[e] * rz;
    o[e] = (v > 0.f) ? v : expm1f(v);
  }
  ((float4v*)out)[idx] = o;
}

// ---------------------------------------------------------------------------
extern "C" void kernel_launch(void* const* d_in, const int* in_sizes, int n_in,
                              void* d_out, int out_size, void* d_ws, size_t ws_size,
                              hipStream_t stream) {
  const int*   adj = (const int*)d_in[0];
  const float* x   = (const float*)d_in[1];
  const float* w   = (const float*)d_in[2];
  const float* a   = (const float*)d_in[3];
  float* out = (float*)d_out;

  // ws usage: ~72 MiB (ws is ~1 GiB — the harness's 0xAA poison fill showed
  // 1.07 GB). hTf (8 MiB f32) lives in d_out transiently; k_out overwrites
  // d_out entirely each call.
  char* ws = (char*)d_ws;
  short*  hT   = (short*)(ws + 0);          // 4 MiB  bf16 h^T [256][8192]
  float*  t1p  = (float*)(ws + 4194304);    // 64 KiB (2 x 8192)
  float*  t2p  = (float*)(ws + 4259840);    // 64 KiB
  float2* e1f1 = (float2*)(ws + 4325376);   // 64 KiB
  float2* ef2  = (float2*)(ws + 4390912);   // 64 KiB
  float*  Zp   = (float*)(ws + 4456448);    // 256 KiB (8 x 8192)
  float*  Np   = (float*)(ws + 8388608);    // 64 MiB  (8 x 8192 x 256)
  float*  hTf  = (float*)d_out;             // 8 MiB  f32 h^T (transient)

  k_hgemm  <<<128, 256, 0, stream>>>(x, w, hT, hTf);
  k_scores1<<<dim3(32, 2), 256, 0, stream>>>(hTf, a, t1p, t2p);
  k_scores2<<<32, 256, 0, stream>>>(t1p, t2p, e1f1, ef2);
  k_gat    <<<dim3(64, 8), 512, 0, stream>>>(adj, hT, e1f1, ef2, Np, Zp);
  k_out    <<<2048, 256, 0, stream>>>(Np, Zp, out);
}